// Round 5
// baseline (70.115 us; speedup 1.0000x reference)
//
#include <hip/hip_runtime.h>
#include <hip/hip_bf16.h>
#include <stdint.h>

// costh[B,CK] = (x/||x||_row) @ (W/||W||_col),  x:[B,D] f32, W:[D,CK] f32
// B=512, D=512, CK=5994*3=17982. Output f32.
// Kernel 1 (xnorm): x -> An normalized bf16 granule tiles (tiny, 512 KB).
// Kernel 2 (gemm_fused): W read f32 COALESCED in-kernel, cvt+transpose via
//   swizzled LDS writes, column sumsq fused, 2-deep pipeline with counted
//   vmcnt + raw barriers, XCD-swizzled grid, winv in epilogue.

#define D_DIM 512
#define BM 128
#define BN 128
#define BK 64
#define KITERS (D_DIM / BK)        // 8
#define TILE_BYTES (64 * BM * 16)  // An per-mtile: 64 granules x 128 rows x 16B = 128KB

typedef __bf16 bf16x8 __attribute__((ext_vector_type(8)));
typedef float f32x4 __attribute__((ext_vector_type(4)));

__device__ __forceinline__ unsigned short f2bf(float f) {
  union { float f; unsigned int u; } v; v.f = f;
  unsigned int u = v.u;
  u += 0x7fffu + ((u >> 16) & 1u);   // RNE
  return (unsigned short)(u >> 16);
}

__device__ __forceinline__ void load_lds16(const void* g, void* l) {
  __builtin_amdgcn_global_load_lds(
      (__attribute__((address_space(1))) void*)(g),
      (__attribute__((address_space(3))) void*)(l), 16, 0, 0);
}

__device__ __forceinline__ int swc(int c) { return c ^ ((c >> 3) & 7); }

// ---------------- kernel 1: x row norms -> An tiled bf16 ----------------
__global__ void xnorm_kernel(const float* __restrict__ x, unsigned short* __restrict__ An) {
  const int t = threadIdx.x;
  const int w = t >> 6, lane = t & 63;
  const int m = blockIdx.x * 4 + w;
  const float* xr = x + (size_t)m * D_DIM + lane * 8;
  float4 a = *(const float4*)(xr);
  float4 c = *(const float4*)(xr + 4);
  float s = a.x * a.x + a.y * a.y + a.z * a.z + a.w * a.w +
            c.x * c.x + c.y * c.y + c.z * c.z + c.w * c.w;
#pragma unroll
  for (int off = 32; off; off >>= 1) s += __shfl_xor(s, off, 64);
  const float inv = 1.f / fmaxf(sqrtf(s), 1e-8f);
  ushort4 o0, o1;
  o0.x = f2bf(a.x * inv); o0.y = f2bf(a.y * inv); o0.z = f2bf(a.z * inv); o0.w = f2bf(a.w * inv);
  o1.x = f2bf(c.x * inv); o1.y = f2bf(c.y * inv); o1.z = f2bf(c.z * inv); o1.w = f2bf(c.w * inv);
  const int mtile = m >> 7, r = m & 127;
  unsigned short* dst = An + (size_t)mtile * (TILE_BYTES / 2) + (size_t)lane * (BM * 8) + r * 8;
  *(ushort4*)dst = o0;
  *(ushort4*)(dst + 4) = o1;
}

// ---------------- kernel 2: fused GEMM ----------------
// LDS: bufA dbuf [0,16K)+[16K,32K), bufB dbuf [32K,48K)+[48K,64K)
__global__ __launch_bounds__(256, 2) void gemm_fused(const unsigned short* __restrict__ An,
                                                     const float* __restrict__ W,
                                                     float* __restrict__ out, int CK) {
  __shared__ __attribute__((aligned(16))) unsigned char lds[65536];
  // bijective XCD swizzle (m204)
  const int total = gridDim.x;
  const int q = total >> 3, rr = total & 7;
  const int lin = blockIdx.x;
  const int xcd = lin & 7, idx = lin >> 3;
  const int wg = ((xcd < rr) ? xcd * (q + 1) : rr * (q + 1) + (xcd - rr) * q) + idx;
  const int ntile = wg >> 2, mtile = wg & 3;

  const int t = threadIdx.x;
  const int lane = t & 63, w = t >> 6;
  const int wm = w >> 1, wn = w & 1;          // wave -> 64x64 quadrant
  const int lrow = lane & 15;
  const int kg = lane >> 4;                   // k-granule slot 0..3

  const unsigned char* srcA = (const unsigned char*)An + (size_t)mtile * TILE_BYTES;
  const int n0 = ntile * BN;

  // B staging mapping: thread (cq, dr) owns granule dr (8 k-rows) x 4 cols
  const int cq = t & 31, dr = t >> 5;
  const int nb = n0 + cq * 4;
  const bool full = (n0 + BN <= CK);

  f32x4 acc[4][4] = {};
  float4 vb[8];                               // B(kt+1) rows dr*8..+7 x cols nb..+3
  float wsq0 = 0.f, wsq1 = 0.f, wsq2 = 0.f, wsq3 = 0.f;

#define BLOAD(kt)                                                              \
  {                                                                            \
    const float* base = W + (size_t)((kt) * BK + dr * 8) * CK;                 \
    if (full) {                                                                \
      _Pragma("unroll")                                                        \
      for (int i = 0; i < 8; ++i) vb[i] = *(const float4*)(base + (size_t)i * CK + nb); \
    } else {                                                                   \
      _Pragma("unroll")                                                        \
      for (int i = 0; i < 8; ++i) {                                            \
        const float* rp = base + (size_t)i * CK;                               \
        vb[i].x = rp[(nb + 0 < CK) ? nb + 0 : CK - 1];                         \
        vb[i].y = rp[(nb + 1 < CK) ? nb + 1 : CK - 1];                         \
        vb[i].z = rp[(nb + 2 < CK) ? nb + 2 : CK - 1];                         \
        vb[i].w = rp[(nb + 3 < CK) ? nb + 3 : CK - 1];                         \
      }                                                                        \
    }                                                                          \
  }

  // convert vb -> bf16 granules, ds_write to bufB sel, accumulate sumsq
#define CVTWRITE(sel)                                                          \
  {                                                                            \
    unsigned char* bBw = lds + 32768 + (sel) * 16384 + dr * 2048;              \
    {                                                                          \
      uint4 o;                                                                 \
      o.x = (unsigned int)f2bf(vb[0].x) | ((unsigned int)f2bf(vb[1].x) << 16); \
      o.y = (unsigned int)f2bf(vb[2].x) | ((unsigned int)f2bf(vb[3].x) << 16); \
      o.z = (unsigned int)f2bf(vb[4].x) | ((unsigned int)f2bf(vb[5].x) << 16); \
      o.w = (unsigned int)f2bf(vb[6].x) | ((unsigned int)f2bf(vb[7].x) << 16); \
      *(uint4*)(bBw + swc(cq * 4 + 0) * 16) = o;                               \
      wsq0 += vb[0].x * vb[0].x + vb[1].x * vb[1].x + vb[2].x * vb[2].x + vb[3].x * vb[3].x \
            + vb[4].x * vb[4].x + vb[5].x * vb[5].x + vb[6].x * vb[6].x + vb[7].x * vb[7].x; \
    }                                                                          \
    {                                                                          \
      uint4 o;                                                                 \
      o.x = (unsigned int)f2bf(vb[0].y) | ((unsigned int)f2bf(vb[1].y) << 16); \
      o.y = (unsigned int)f2bf(vb[2].y) | ((unsigned int)f2bf(vb[3].y) << 16); \
      o.z = (unsigned int)f2bf(vb[4].y) | ((unsigned int)f2bf(vb[5].y) << 16); \
      o.w = (unsigned int)f2bf(vb[6].y) | ((unsigned int)f2bf(vb[7].y) << 16); \
      *(uint4*)(bBw + swc(cq * 4 + 1) * 16) = o;                               \
      wsq1 += vb[0].y * vb[0].y + vb[1].y * vb[1].y + vb[2].y * vb[2].y + vb[3].y * vb[3].y \
            + vb[4].y * vb[4].y + vb[5].y * vb[5].y + vb[6].y * vb[6].y + vb[7].y * vb[7].y; \
    }                                                                          \
    {                                                                          \
      uint4 o;                                                                 \
      o.x = (unsigned int)f2bf(vb[0].z) | ((unsigned int)f2bf(vb[1].z) << 16); \
      o.y = (unsigned int)f2bf(vb[2].z) | ((unsigned int)f2bf(vb[3].z) << 16); \
      o.z = (unsigned int)f2bf(vb[4].z) | ((unsigned int)f2bf(vb[5].z) << 16); \
      o.w = (unsigned int)f2bf(vb[6].z) | ((unsigned int)f2bf(vb[7].z) << 16); \
      *(uint4*)(bBw + swc(cq * 4 + 2) * 16) = o;                               \
      wsq2 += vb[0].z * vb[0].z + vb[1].z * vb[1].z + vb[2].z * vb[2].z + vb[3].z * vb[3].z \
            + vb[4].z * vb[4].z + vb[5].z * vb[5].z + vb[6].z * vb[6].z + vb[7].z * vb[7].z; \
    }                                                                          \
    {                                                                          \
      uint4 o;                                                                 \
      o.x = (unsigned int)f2bf(vb[0].w) | ((unsigned int)f2bf(vb[1].w) << 16); \
      o.y = (unsigned int)f2bf(vb[2].w) | ((unsigned int)f2bf(vb[3].w) << 16); \
      o.z = (unsigned int)f2bf(vb[4].w) | ((unsigned int)f2bf(vb[5].w) << 16); \
      o.w = (unsigned int)f2bf(vb[6].w) | ((unsigned int)f2bf(vb[7].w) << 16); \
      *(uint4*)(bBw + swc(cq * 4 + 3) * 16) = o;                               \
      wsq3 += vb[0].w * vb[0].w + vb[1].w * vb[1].w + vb[2].w * vb[2].w + vb[3].w * vb[3].w \
            + vb[4].w * vb[4].w + vb[5].w * vb[5].w + vb[6].w * vb[6].w + vb[7].w * vb[7].w; \
    }                                                                          \
  }

  // A staging: 16 KB linear, 4 rounds of 4KB (wave-linear lane x 16B)
#define ALDS(kt, sel)                                                          \
  {                                                                            \
    const size_t koff = (size_t)(kt) * 16384;                                  \
    unsigned char* bAw = lds + (sel) * 16384;                                  \
    _Pragma("unroll")                                                          \
    for (int c = 0; c < 4; ++c) {                                              \
      const int off = c * 4096 + t * 16;                                       \
      load_lds16(srcA + koff + off, bAw + off);                                \
    }                                                                          \
  }

  // ---- prologue ----
  BLOAD(0);          // 8 vmem -> vb
  ALDS(0, 0);        // 4 gload_lds (issued after B(0))
  CVTWRITE(0);       // compiler waits vb (vmcnt leaves A in flight)
  BLOAD(1);          // 8 vmem
  __builtin_amdgcn_sched_barrier(0);
  asm volatile("s_waitcnt vmcnt(8)" ::: "memory");   // retire A(0), keep B(1) in flight
  asm volatile("s_waitcnt lgkmcnt(0)" ::: "memory");
  __builtin_amdgcn_s_barrier();
  __builtin_amdgcn_sched_barrier(0);

  // ---- main loop ----
  for (int kt = 0; kt < KITERS; ++kt) {
    const int cur = kt & 1;
    const unsigned char* bA = lds + cur * 16384;
    const unsigned char* bB = lds + 32768 + cur * 16384;

    // fragment reads from current buffers
    bf16x8 afrag[2][4], bfrag[2][4];
#pragma unroll
    for (int h = 0; h < 2; ++h)
#pragma unroll
      for (int i = 0; i < 4; ++i) {
        afrag[h][i] = *(const bf16x8*)(bA + (kg + 4 * h) * 2048 + (wm * 64 + i * 16 + lrow) * 16);
        bfrag[h][i] = *(const bf16x8*)(bB + (kg + 4 * h) * 2048 + swc(wn * 64 + i * 16 + lrow) * 16);
      }

    // stage next: cvt B(kt+1) -> other bufB; issue A(kt+1) lds; issue B(kt+2)
    if (kt + 1 < KITERS) {
      CVTWRITE(cur ^ 1);
      ALDS(kt + 1, cur ^ 1);
      if (kt + 2 < KITERS) BLOAD(kt + 2);
    }

    // MFMA (covers the staging latency)
#pragma unroll
    for (int i = 0; i < 4; ++i)
#pragma unroll
      for (int j = 0; j < 4; ++j) {
        acc[i][j] = __builtin_amdgcn_mfma_f32_16x16x32_bf16(afrag[0][i], bfrag[0][j], acc[i][j], 0, 0, 0);
        acc[i][j] = __builtin_amdgcn_mfma_f32_16x16x32_bf16(afrag[1][i], bfrag[1][j], acc[i][j], 0, 0, 0);
      }

    __builtin_amdgcn_sched_barrier(0);
    if (kt < KITERS - 2) {
      // outstanding: A(kt+1) x4 (older) + B(kt+2) x8 (newer) -> retire A only
      asm volatile("s_waitcnt vmcnt(8)" ::: "memory");
    } else {
      asm volatile("s_waitcnt vmcnt(0)" ::: "memory");
    }
    asm volatile("s_waitcnt lgkmcnt(0)" ::: "memory");
    __builtin_amdgcn_s_barrier();
    __builtin_amdgcn_sched_barrier(0);
  }

  // ---- winv reduction (LDS free now) ----
  float* red = (float*)lds;                   // [8][128]
  float* winv = (float*)(lds + 4096);         // [128]
  *(float4*)(&red[dr * 128 + cq * 4]) = make_float4(wsq0, wsq1, wsq2, wsq3);
  __syncthreads();
  if (t < 128) {
    float s = 0.f;
#pragma unroll
    for (int k = 0; k < 8; ++k) s += red[k * 128 + t];
    winv[t] = 1.f / fmaxf(sqrtf(s), 1e-8f);
  }
  __syncthreads();

  // ---- epilogue: C layout col=lane&15, row=(lane>>4)*4+reg ----
#pragma unroll
  for (int j = 0; j < 4; ++j) {
    const int cl = wn * 64 + j * 16 + lrow;
    const int col = n0 + cl;
    if (col < CK) {
      const float wv = winv[cl];
#pragma unroll
      for (int i = 0; i < 4; ++i) {
#pragma unroll
        for (int jj = 0; jj < 4; ++jj) {
          const int row = mtile * BM + wm * 64 + i * 16 + kg * 4 + jj;
          out[(size_t)row * CK + col] = acc[i][j][jj] * wv;
        }
      }
    }
  }
}

extern "C" void kernel_launch(void* const* d_in, const int* in_sizes, int n_in,
                              void* d_out, int out_size, void* d_ws, size_t ws_size,
                              hipStream_t stream) {
  const float* x = (const float*)d_in[0];
  const float* W = (const float*)d_in[1];
  float* out = (float*)d_out;
  const int Bn = in_sizes[0] / D_DIM;     // 512
  const int CK = in_sizes[1] / D_DIM;     // 17982
  const int ntiles = (CK + BN - 1) / BN;  // 141
  const int mtiles = Bn / BM;             // 4

  unsigned short* An = (unsigned short*)d_ws;  // 512 KB

  hipLaunchKernelGGL(xnorm_kernel, dim3(Bn / 4), dim3(256), 0, stream, x, An);
  hipLaunchKernelGGL(gemm_fused, dim3(ntiles * mtiles), dim3(256), 0, stream, An, W, out, CK);
}

// Round 6
// 35.882 us; speedup vs baseline: 1.9540x; 1.9540x over previous
//
#include <hip/hip_runtime.h>
#include <hip/hip_bf16.h>
#include <stdint.h>

// costh[B,CK] = (x/||x||_row) @ (W/||W||_col),  x:[B,D] f32, W:[D,CK] f32
// B=512, D=512, CK=5994*3=17982. Output f32.
// Kernel 1 (prep): W -> Wt bf16 granule tiles (register transpose, coalesced both
//   sides) + per-column partial sumsq; x -> An normalized tiles (extra blocks).
// Kernel 2 (gemm): 128x128 tile, BK=32, 3-buffer rotation with counted vmcnt
//   (prefetch never drained mid-loop), 3 blocks/CU, LDS-staged full-line epilogue.

#define D_DIM 512
#define BM 128
#define BN 128
#define KITERS 16                  // K-steps of 32
#define TILE_BYTES (64 * BM * 16)  // 131072 B per 128-row tile

typedef __bf16 bf16x8 __attribute__((ext_vector_type(8)));
typedef float f32x4 __attribute__((ext_vector_type(4)));

__device__ __forceinline__ unsigned short f2bf(float f) {
  union { float f; unsigned int u; } v; v.f = f;
  unsigned int u = v.u;
  u += 0x7fffu + ((u >> 16) & 1u);   // RNE
  return (unsigned short)(u >> 16);
}

__device__ __forceinline__ void load_lds16(const void* g, void* l) {
  __builtin_amdgcn_global_load_lds(
      (__attribute__((address_space(1))) void*)(g),
      (__attribute__((address_space(3))) void*)(l), 16, 0, 0);
}

// ---------------- kernel 1: prep (wtrans blocks + xnorm blocks) ----------------
__global__ void prep_kernel(const float* __restrict__ x, const float* __restrict__ W,
                            unsigned short* __restrict__ An, unsigned short* __restrict__ Wt,
                            float* __restrict__ partial, int CK, int NT128, int nWtBlocks) {
  const int b = blockIdx.x;
  const int t = threadIdx.x;
  if (b < nWtBlocks) {
    __shared__ float red[8 * 128];
    const int ntile = b >> 3, gb = b & 7;
    const int cq = t & 31, dr = t >> 5;
    const int n0 = ntile * BN;
    const int nb = n0 + cq * 4;
    const int g = gb * 8 + dr;               // granule (k/8)
    float ss0 = 0.f, ss1 = 0.f, ss2 = 0.f, ss3 = 0.f;
    unsigned int gr[4][4];                   // [col][pair] packed bf16x2
    if (n0 + BN <= CK) {
#pragma unroll
      for (int i = 0; i < 8; i += 2) {
        float4 v0 = *(const float4*)(W + (size_t)(g * 8 + i) * CK + nb);
        float4 v1 = *(const float4*)(W + (size_t)(g * 8 + i + 1) * CK + nb);
        ss0 += v0.x * v0.x + v1.x * v1.x; ss1 += v0.y * v0.y + v1.y * v1.y;
        ss2 += v0.z * v0.z + v1.z * v1.z; ss3 += v0.w * v0.w + v1.w * v1.w;
        gr[0][i >> 1] = (unsigned int)f2bf(v0.x) | ((unsigned int)f2bf(v1.x) << 16);
        gr[1][i >> 1] = (unsigned int)f2bf(v0.y) | ((unsigned int)f2bf(v1.y) << 16);
        gr[2][i >> 1] = (unsigned int)f2bf(v0.z) | ((unsigned int)f2bf(v1.z) << 16);
        gr[3][i >> 1] = (unsigned int)f2bf(v0.w) | ((unsigned int)f2bf(v1.w) << 16);
      }
    } else {
      float acc_ss[4] = {0.f, 0.f, 0.f, 0.f};
#pragma unroll
      for (int i = 0; i < 8; i += 2) {
#pragma unroll
        for (int e = 0; e < 4; ++e) {
          const int n = nb + e;
          const float f0 = (n < CK) ? W[(size_t)(g * 8 + i) * CK + n] : 0.f;
          const float f1 = (n < CK) ? W[(size_t)(g * 8 + i + 1) * CK + n] : 0.f;
          acc_ss[e] += f0 * f0 + f1 * f1;
          gr[e][i >> 1] = (unsigned int)f2bf(f0) | ((unsigned int)f2bf(f1) << 16);
        }
      }
      ss0 = acc_ss[0]; ss1 = acc_ss[1]; ss2 = acc_ss[2]; ss3 = acc_ss[3];
    }
    unsigned short* dst = Wt + (size_t)ntile * (TILE_BYTES / 2) + (size_t)g * (BM * 8) + (size_t)cq * 32;
#pragma unroll
    for (int e = 0; e < 4; ++e) {
      uint4 o; o.x = gr[e][0]; o.y = gr[e][1]; o.z = gr[e][2]; o.w = gr[e][3];
      *(uint4*)(dst + e * 8) = o;
    }
    *(float4*)(&red[dr * 128 + cq * 4]) = make_float4(ss0, ss1, ss2, ss3);
    __syncthreads();
    if (t < 128) {
      float s = 0.f;
#pragma unroll
      for (int k = 0; k < 8; ++k) s += red[k * 128 + t];
      partial[(size_t)gb * NT128 + n0 + t] = s;
    }
  } else {
    // xnorm: 4 rows per block, one wave per row
    const int w = t >> 6, lane = t & 63;
    const int m = (b - nWtBlocks) * 4 + w;
    const float* xr = x + (size_t)m * D_DIM + lane * 8;
    float4 a = *(const float4*)(xr);
    float4 c = *(const float4*)(xr + 4);
    float s = a.x * a.x + a.y * a.y + a.z * a.z + a.w * a.w +
              c.x * c.x + c.y * c.y + c.z * c.z + c.w * c.w;
#pragma unroll
    for (int off = 32; off; off >>= 1) s += __shfl_xor(s, off, 64);
    const float inv = 1.f / fmaxf(sqrtf(s), 1e-8f);
    ushort4 o0, o1;
    o0.x = f2bf(a.x * inv); o0.y = f2bf(a.y * inv); o0.z = f2bf(a.z * inv); o0.w = f2bf(a.w * inv);
    o1.x = f2bf(c.x * inv); o1.y = f2bf(c.y * inv); o1.z = f2bf(c.z * inv); o1.w = f2bf(c.w * inv);
    const int mtile = m >> 7, r = m & 127;
    unsigned short* dst = An + (size_t)mtile * (TILE_BYTES / 2) + (size_t)lane * (BM * 8) + r * 8;
    *(ushort4*)dst = o0;
    *(ushort4*)(dst + 4) = o1;
  }
}

// ---------------- kernel 2: GEMM, BK=32, 3-buffer counted-vmcnt pipeline ----------------
// LDS: 3 staging buffers of 16KB (A 8K + B 8K); epilogue reuses [1024, 35840).
__global__ __launch_bounds__(256, 3) void gemm_kernel(const unsigned short* __restrict__ An,
                                                      const unsigned short* __restrict__ Wt,
                                                      const float* __restrict__ partial,
                                                      float* __restrict__ out, int CK, int NT128) {
  __shared__ __attribute__((aligned(16))) unsigned char lds[49152];
  // bijective XCD swizzle (m204)
  const int total = gridDim.x;
  const int q = total >> 3, rr = total & 7;
  const int lin = blockIdx.x;
  const int xcd = lin & 7, idx = lin >> 3;
  const int wg = ((xcd < rr) ? xcd * (q + 1) : rr * (q + 1) + (xcd - rr) * q) + idx;
  const int ntile = wg >> 2, mtile = wg & 3;

  const int t = threadIdx.x;
  const int lane = t & 63, w = t >> 6;
  const int wm = w >> 1, wn = w & 1;          // wave -> 64x64 quadrant
  const int lrow = lane & 15;
  const int kg = lane >> 4;                   // k-granule slot 0..3

  const unsigned char* srcA = (const unsigned char*)An + (size_t)mtile * TILE_BYTES;
  const unsigned char* srcB = (const unsigned char*)Wt + (size_t)ntile * TILE_BYTES;
  const int n0 = ntile * BN;
  const bool full = (n0 + BN <= CK);

  f32x4 acc[4][4] = {};

  // one K-step = 8KB A + 8KB B; 2+2 gload_lds per thread
#define STAGE(kt, sel)                                                        \
  {                                                                           \
    const size_t koff = (size_t)(kt) * 8192;                                  \
    unsigned char* bAw = lds + (sel) * 16384;                                 \
    unsigned char* bBw = bAw + 8192;                                          \
    _Pragma("unroll")                                                         \
    for (int c = 0; c < 2; ++c) {                                             \
      const int off = c * 4096 + t * 16;                                      \
      load_lds16(srcA + koff + off, bAw + off);                               \
    }                                                                         \
    _Pragma("unroll")                                                         \
    for (int c = 0; c < 2; ++c) {                                             \
      const int off = c * 4096 + t * 16;                                      \
      load_lds16(srcB + koff + off, bBw + off);                               \
    }                                                                         \
  }

  STAGE(0, 0);

#pragma unroll
  for (int kt = 0; kt < KITERS; ++kt) {
    if (kt + 1 < KITERS) STAGE(kt + 1, (kt + 1) % 3);   // prefetch stays in flight
    __builtin_amdgcn_sched_barrier(0);
    if (kt + 1 < KITERS) {
      asm volatile("s_waitcnt vmcnt(4)" ::: "memory");  // retire STAGE(kt), keep STAGE(kt+1)
    } else {
      asm volatile("s_waitcnt vmcnt(0)" ::: "memory");
    }
    __builtin_amdgcn_s_barrier();
    __builtin_amdgcn_sched_barrier(0);

    const unsigned char* bA = lds + (kt % 3) * 16384;
    const unsigned char* bB = bA + 8192;
    bf16x8 afrag[4], bfrag[4];
#pragma unroll
    for (int i = 0; i < 4; ++i) {
      afrag[i] = *(const bf16x8*)(bA + kg * 2048 + (wm * 64 + i * 16 + lrow) * 16);
      bfrag[i] = *(const bf16x8*)(bB + kg * 2048 + (wn * 64 + i * 16 + lrow) * 16);
    }
#pragma unroll
    for (int i = 0; i < 4; ++i)
#pragma unroll
      for (int j = 0; j < 4; ++j)
        acc[i][j] = __builtin_amdgcn_mfma_f32_16x16x32_bf16(afrag[i], bfrag[j], acc[i][j], 0, 0, 0);
  }

  // ---- winv ----
  __syncthreads();                       // all waves done with staging LDS
  float* winv = (float*)lds;             // 128 f32 at base
  if (t < 128) {
    float s = 0.f;
#pragma unroll
    for (int k = 0; k < 8; ++k) s += partial[(size_t)k * NT128 + n0 + t];
    winv[t] = 1.f / fmaxf(sqrtf(s), 1e-8f);
  }
  __syncthreads();
  float wv[4];
#pragma unroll
  for (int j = 0; j < 4; ++j) wv[j] = winv[wn * 64 + j * 16 + lrow];

  // ---- epilogue ----
  // C frag layout: col=lane&15, row=(lane>>4)*4+reg. Stage per-wave 32x64 f32
  // halves in wave-private padded LDS (stride 68 f32 = 272B, 16B-aligned rows),
  // then float4 stores: 256B contiguous per row -> full-line HBM writes.
  if (full) {
    float* stg = (float*)(lds + 1024) + w * 2176;   // 32*68 floats per wave
    const int l15 = lane & 15, l4 = lane >> 4;
#pragma unroll
    for (int half = 0; half < 2; ++half) {
#pragma unroll
      for (int di = 0; di < 2; ++di)
#pragma unroll
        for (int j = 0; j < 4; ++j)
#pragma unroll
          for (int jj = 0; jj < 4; ++jj)
            stg[(di * 16 + kg * 4 + jj) * 68 + j * 16 + lrow] = acc[half * 2 + di][j][jj] * wv[j];
      // wave-private region: per-wave lgkm ordering suffices, no barrier
#pragma unroll
      for (int s = 0; s < 8; ++s) {
        const int rl = s * 4 + l4;
        float4 v = *(float4*)&stg[rl * 68 + l15 * 4];
        const int row = mtile * BM + wm * 64 + half * 32 + rl;
        *(float4*)&out[(size_t)row * CK + n0 + wn * 64 + l15 * 4] = v;
      }
    }
  } else {
    // tail ntile only (1 of 141): scalar stores with bounds check
#pragma unroll
    for (int j = 0; j < 4; ++j) {
      const int col = n0 + wn * 64 + j * 16 + lrow;
      if (col < CK) {
#pragma unroll
        for (int i = 0; i < 4; ++i)
#pragma unroll
          for (int jj = 0; jj < 4; ++jj) {
            const int row = mtile * BM + wm * 64 + i * 16 + kg * 4 + jj;
            out[(size_t)row * CK + col] = acc[i][j][jj] * wv[j];
          }
      }
    }
  }
}

extern "C" void kernel_launch(void* const* d_in, const int* in_sizes, int n_in,
                              void* d_out, int out_size, void* d_ws, size_t ws_size,
                              hipStream_t stream) {
  const float* x = (const float*)d_in[0];
  const float* W = (const float*)d_in[1];
  float* out = (float*)d_out;
  const int Bn = in_sizes[0] / D_DIM;     // 512
  const int CK = in_sizes[1] / D_DIM;     // 17982
  const int ntiles = (CK + BN - 1) / BN;  // 141
  const int mtiles = Bn / BM;             // 4
  const int NT128 = ntiles * BN;          // 18048

  unsigned char* ws = (unsigned char*)d_ws;
  float* partial = (float*)ws;                                  // 8*NT128*4 = 577536 B
  unsigned short* An = (unsigned short*)(ws + 8 * (size_t)NT128 * 4);
  unsigned short* Wt = (unsigned short*)(ws + 8 * (size_t)NT128 * 4 + (size_t)mtiles * TILE_BYTES);

  const int nWtBlocks = ntiles * 8;
  const int nXBlocks = Bn / 4;            // 128
  hipLaunchKernelGGL(prep_kernel, dim3(nWtBlocks + nXBlocks), dim3(256), 0, stream,
                     x, W, An, Wt, partial, CK, NT128, nWtBlocks);
  hipLaunchKernelGGL(gemm_kernel, dim3(ntiles * mtiles), dim3(256), 0, stream,
                     An, Wt, partial, out, CK, NT128);
}